// Round 3
// 131.460 us; speedup vs baseline: 1.0591x; 1.0591x over previous
//
#include <hip/hip_runtime.h>
#include <hip/hip_bf16.h>

#define T 50
#define NB 64
#define NS 512
#define START_TAG 48
#define STOP_TAG 49
#define PITCH 76       // LDS halfword pitch for 64x64 f16 C (bank-spread)

typedef _Float16 f16_t;
typedef _Float16 f16x2 __attribute__((ext_vector_type(2)));
typedef _Float16 f16x4 __attribute__((ext_vector_type(4)));
typedef _Float16 f16x8 __attribute__((ext_vector_type(8)));
typedef float    f32x4 __attribute__((ext_vector_type(4)));

static constexpr float LOG2E = 1.4426950408889634f;
static constexpr float LN2F  = 0.6931471805599453f;
static constexpr float S_E   = 6.0f;     // static log2 shift folded out of E
#define NEG_BIG (-1.0e38f)

__device__ __forceinline__ float fexp2(float x) { return __builtin_amdgcn_exp2f(x); }
__device__ __forceinline__ float flog2(float x) { return __builtin_amdgcn_logf(x); }
__device__ __forceinline__ f16x2 bcast_h2(f16x2 v, int src) {
    unsigned u = __builtin_amdgcn_readlane(__builtin_bit_cast(unsigned, v), src);
    return __builtin_bit_cast(f16x2, u);
}
__device__ __forceinline__ f16x2 pack_h2(float a, float b) {
    return __builtin_bit_cast(f16x2, __builtin_amdgcn_cvt_pkrtz(a, b));
}

// =====================================================================
// Kernel 1: per (batch, chunk) compute P_c = prod_{t in chunk} (E * D_t)
// as CHLT sequential 64x64x64 f16 MFMA products.
//  - column permutation pi(n) = 4*(n&15) + (n>>4) baked into the E
//    fragments: MFMA slot n = 16*c2 + l15 holds ACTUAL column 4*l15+c2,
//    so a lane's 4 outputs per row are contiguous -> one ds_write_b64
//    per row (4 stores/step instead of 16 scalar b16), and the 4 column
//    scales come from one ds_read_b128.
//  - renorm descale folded into the column scale (post-MFMA, f32):
//    (C*dsc)*E*diag(cs) == C*E*diag(cs*dsc) exactly (dsc = 2^-e).
//    Removes 16 f16 muls/step and takes sMax off the pre-MFMA chain.
//  - NCHT=16/CHLT=32: half the serial depth, 4 blocks/CU.
// C is stored TRANSPOSED (C^T row-major f16) for the combine kernel's
// coalesced per-lane column reads. LDS layout of C stays NATURAL
// row-major (pi only remaps MFMA slots), so A-reads and the final
// transposed store are unchanged.
// =====================================================================
template<int NCHT, int CHLT>
__global__ __launch_bounds__(256, 1)
void crf_chunk(const float* __restrict__ feats, const int* __restrict__ mask,
               const float* __restrict__ trans, f16_t* __restrict__ wsCt,
               float* __restrict__ wsD) {
    const int c    = blockIdx.x;          // chunk
    const int b    = blockIdx.y;          // batch
    const int tid  = threadIdx.x;
    const int w    = tid >> 6;
    const int lane = tid & 63;
    const int l15  = lane & 15;
    const int q    = lane >> 4;

    __shared__ f16_t sC[2][64 * PITCH];   // C_raw, double-buffered (toggle cb)
    __shared__ float sF[CHLT][64];        // 2^(f_t * log2e) per step/col (preloaded)
    __shared__ int   sMk[CHLT];           // masks (preloaded)
    __shared__ float sMax[2][4];          // per-wave max of C_raw, toggles with cb

    const int t0  = c * CHLT + 1;
    const int nst = NS - t0 < CHLT ? NS - t0 : CHLT;

    // ---- E fragments, column-permuted. Slot n = 16*c2 + l15 -> actual
    // column j = 4*l15 + c2. Row index k = 32*kb + q*8 + jj (natural).
    f16x8 Efrag[2][4];
    #pragma unroll
    for (int kb = 0; kb < 2; kb++)
        #pragma unroll
        for (int c2 = 0; c2 < 4; c2++) {
            f16x8 v;
            const int j = 4 * l15 + c2;
            #pragma unroll
            for (int jj = 0; jj < 8; jj++) {
                int kk = 32 * kb + q * 8 + jj;
                float x = 0.f;
                if (kk < T && j < T) x = fexp2(fmaf(trans[kk * T + j], LOG2E, -S_E));
                v[jj] = (f16_t)x;
            }
            Efrag[kb][c2] = v;
        }

    // ---- bulk preload: feats block (exp2 once) + masks; zero global in loop
    for (int r = w; r < CHLT; r += 4) {
        int tl = t0 + r; tl = tl < NS ? tl : NS - 1;
        float fv = (lane < T && r < nst) ? feats[((size_t)b * NS + tl) * T + lane] : 0.f;
        sF[r][lane] = (lane < T && r < nst) ? fexp2(fv * LOG2E) : 0.f;
    }
    if (tid < CHLT) {
        int tl = t0 + tid; tl = tl < NS ? tl : NS - 1;
        sMk[tid] = (tid < nst) ? mask[b * NS + tl] : 0;
    }

    // ---- init: C = I (64x64) in buf 0, max = 1
    for (int idx = tid; idx < 64 * PITCH; idx += 256) sC[0][idx] = (f16_t)0.f;
    if (tid < 64) sC[0][tid * PITCH + tid] = (f16_t)1.f;
    if (tid < 4)  sMax[0][tid] = 1.f;
    __syncthreads();

    float D  = 0.f;
    int   cb = 0;
    int   mk = sMk[0];

    for (int s = 0; s < nst; s++) {
        const bool doit = (mk != 0);
        mk = (s + 1 < CHLT) ? sMk[s + 1] : 0;   // prefetch next mask (LDS)

        if (doit) {
            // A fragments: RAW f16 rows of C (no descale mul; folded into cs2)
            f16x8 A[2];
            #pragma unroll
            for (int kb = 0; kb < 2; kb++) {
                const int base = (16 * w + l15) * PITCH + 32 * kb + q * 8;
                f16x4 lo = *(const f16x4*)&sC[cb][base];
                f16x4 hi = *(const f16x4*)&sC[cb][base + 4];
                f16x8 a;
                #pragma unroll
                for (int z = 0; z < 4; z++) { a[z] = lo[z]; a[z + 4] = hi[z]; }
                A[kb] = a;
            }

            // 8 MFMAs: C_next rows [16w,16w+16) x all 4 col-blocks (slot space)
            f32x4 acc[4];
            #pragma unroll
            for (int c2 = 0; c2 < 4; c2++) {
                acc[c2] = __builtin_amdgcn_mfma_f32_16x16x32_f16(A[0], Efrag[0][c2],
                                                                 (f32x4){0.f,0.f,0.f,0.f}, 0, 0, 0);
                acc[c2] = __builtin_amdgcn_mfma_f32_16x16x32_f16(A[1], Efrag[1][c2],
                                                                 acc[c2], 0, 0, 0);
            }

            // renorm shift from previous step's max (clamped so 2^-e fits f16);
            // applied post-MFMA in f32 (exact pow2 scaling, commutes)
            float mx4 = fmaxf(fmaxf(sMax[cb][0], sMax[cb][1]),
                              fmaxf(sMax[cb][2], sMax[cb][3]));
            int ebits = (int)((__float_as_uint(mx4) >> 23) & 255) - 127;
            ebits = ebits > 14 ? 14 : (ebits < -14 ? -14 : ebits);
            const float descale = __uint_as_float((unsigned)(127 - ebits) << 23);
            D += (float)ebits + S_E;

            // column scales for actual cols 4*l15..4*l15+3 (one b128 read)
            f32x4 csv = *(const f32x4*)&sF[s][4 * l15];
            f32x4 cs2;
            #pragma unroll
            for (int c2 = 0; c2 < 4; c2++) cs2[c2] = csv[c2] * descale;

            // scale, track max, pack 4 contiguous cols -> one b64 store per row
            const int nb2 = cb ^ 1;
            float wmax = 0.f;
            #pragma unroll
            for (int r = 0; r < 4; r++) {
                f16x4 hv;
                #pragma unroll
                for (int c2 = 0; c2 < 4; c2++) {
                    float v = acc[c2][r] * cs2[c2];
                    wmax = fmaxf(wmax, v);
                    hv[c2] = (f16_t)v;
                }
                *(f16x4*)&sC[nb2][(16 * w + 4 * q + r) * PITCH + 4 * l15] = hv;
            }
            #pragma unroll
            for (int off = 32; off > 0; off >>= 1)
                wmax = fmaxf(wmax, __shfl_xor(wmax, off, 64));
            if (lane == 0) sMax[nb2][w] = wmax;
        }

        __syncthreads();
        if (doit) cb ^= 1;
    }

    // ---- store C TRANSPOSED: wsCt[.. + col*64 + row] = C[row][col]
    {
        const int col = tid >> 2;
        const int r0  = (tid & 3) << 4;
        unsigned short tmp[16];
        #pragma unroll
        for (int r = 0; r < 16; r++)
            tmp[r] = __builtin_bit_cast(unsigned short, sC[cb][(r0 + r) * PITCH + col]);
        f16_t* dst = wsCt + ((size_t)(b * NCHT + c)) * 4096 + col * 64 + r0;
        ((int4*)dst)[0] = *(const int4*)&tmp[0];
        ((int4*)dst)[1] = *(const int4*)&tmp[8];
        if (tid == 0) wsD[b * NCHT + c] = D;
    }
}

// =====================================================================
// Kernel 2: one wave per batch, no LDS, no barriers. Lane j holds column j
// of each chunk matrix (= C^T row j, contiguous 128 B) in registers,
// register-prefetched one chunk ahead. part = part (x) P_c via true-max
// shift + packed-f16 dot2 (25 x readlane + v_dot2_f32_f16).
// =====================================================================
template<int NCHT>
__global__ __launch_bounds__(64, 1)
void crf_combine(const float* __restrict__ feats, const int* __restrict__ mask,
                 const int* __restrict__ tags, const float* __restrict__ trans,
                 const f16_t* __restrict__ wsCt, const float* __restrict__ wsD,
                 float* __restrict__ out) {
    const int b    = blockIdx.x;
    const int lane = threadIdx.x;

    // ---------------- gold score ----------------
    float gsum = 0.f;
    int   lcnt = 0;
    for (int s = lane; s < NS; s += 64) {
        int   m  = mask[b * NS + s];
        int   tg = tags[b * NS + s];
        int   pv = (s == 0) ? START_TAG : tags[b * NS + s - 1];
        float e  = feats[((size_t)b * NS + s) * T + tg];
        float tr = trans[pv * T + tg];
        if (m) { gsum += e + tr; lcnt += 1; }
    }
    #pragma unroll
    for (int off = 32; off > 0; off >>= 1) {
        gsum += __shfl_down(gsum, off, 64);
        lcnt += __shfl_down(lcnt, off, 64);
    }
    float goldb = 0.f;
    if (lane == 0) goldb = gsum + trans[tags[b * NS + lcnt - 1] * T + STOP_TAG];

    // ---------------- part init (t = 0), log2 domain ----------------
    float part = (lane < T)
        ? (feats[(size_t)b * NS * T + lane] + trans[START_TAG * T + lane]) * LOG2E
        : NEG_BIG;

    // ---------------- shifts + chunk 0 matrix into registers ----------------
    float Dv[NCHT];
    #pragma unroll
    for (int c = 0; c < NCHT; c++) Dv[c] = wsD[b * NCHT + c];

    int cur[32], nxt[32];
    {
        const f16_t* src = wsCt + (size_t)b * NCHT * 4096 + lane * 64;
        #pragma unroll
        for (int kk = 0; kk < 8; kk++)
            *(int4*)&cur[4 * kk] = ((const int4*)src)[kk];
    }

    #pragma unroll
    for (int c = 0; c < NCHT; c++) {
        if (c + 1 < NCHT) {
            const f16_t* src = wsCt + (size_t)(b * NCHT + c + 1) * 4096 + lane * 64;
            #pragma unroll
            for (int kk = 0; kk < 8; kk++)
                *(int4*)&nxt[4 * kk] = ((const int4*)src)[kk];
        }

        // true-max shift (required: ex must fit packed f16)
        float sft = part;
        #pragma unroll
        for (int off = 32; off > 0; off >>= 1) sft = fmaxf(sft, __shfl_xor(sft, off, 64));
        float ex  = fexp2(part - sft);
        float exo = __shfl_xor(ex, 1, 64);
        f16x2 pk  = pack_h2(ex, exo);     // even lane 2k holds (ex[2k], ex[2k+1])

        float a0 = 0.f, a1 = 0.f, a2 = 0.f, a3 = 0.f;
        #pragma unroll
        for (int k = 0; k < 25; k += 4) {
            a0 = __builtin_amdgcn_fdot2(bcast_h2(pk, 2 * k), __builtin_bit_cast(f16x2, cur[k]), a0, false);
            if (k + 1 < 25) a1 = __builtin_amdgcn_fdot2(bcast_h2(pk, 2 * (k + 1)), __builtin_bit_cast(f16x2, cur[k + 1]), a1, false);
            if (k + 2 < 25) a2 = __builtin_amdgcn_fdot2(bcast_h2(pk, 2 * (k + 2)), __builtin_bit_cast(f16x2, cur[k + 2]), a2, false);
            if (k + 3 < 25) a3 = __builtin_amdgcn_fdot2(bcast_h2(pk, 2 * (k + 3)), __builtin_bit_cast(f16x2, cur[k + 3]), a3, false);
        }
        part = sft + Dv[c] + flog2((a0 + a1) + (a2 + a3));

        if (c + 1 < NCHT) {
            #pragma unroll
            for (int kk = 0; kk < 32; kk++) cur[kk] = nxt[kk];
        }
    }

    // ---------------- terminal LSE to STOP + output ----------------
    float v = (lane < T) ? part + trans[lane * T + STOP_TAG] * LOG2E : NEG_BIG;
    float mx = v;
    #pragma unroll
    for (int off = 32; off > 0; off >>= 1) mx = fmaxf(mx, __shfl_xor(mx, off, 64));
    float ee = (lane < T) ? fexp2(v - mx) : 0.f;
    #pragma unroll
    for (int off = 32; off > 0; off >>= 1) ee += __shfl_xor(ee, off, 64);
    if (lane == 0) {
        float fwd = (mx + flog2(ee)) * LN2F;   // back to nats
        atomicAdd(out, fwd - goldb);
    }
}

extern "C" void kernel_launch(void* const* d_in, const int* in_sizes, int n_in,
                              void* d_out, int out_size, void* d_ws, size_t ws_size,
                              hipStream_t stream) {
    const float* feats = (const float*)d_in[0];
    const int*   mask  = (const int*)d_in[1];
    const int*   tags  = (const int*)d_in[2];
    const float* trans = (const float*)d_in[3];
    float* out = (float*)d_out;

    (void)hipMemsetAsync(out, 0, sizeof(float) * out_size, stream);

    const size_t matBytes16 = (size_t)NB * 16 * 4096 * sizeof(f16_t);
    const size_t need16     = matBytes16 + (size_t)NB * 16 * sizeof(float);

    if (ws_size >= need16) {
        // preferred: 16 chunks x 32 steps -> 1024 blocks (4/CU), depth 32
        f16_t* wsCt = (f16_t*)d_ws;
        float* wsD  = (float*)((char*)d_ws + matBytes16);
        crf_chunk<16, 32><<<dim3(16, NB), 256, 0, stream>>>(feats, mask, trans, wsCt, wsD);
        crf_combine<16><<<NB, 64, 0, stream>>>(feats, mask, tags, trans, wsCt, wsD, out);
    } else {
        // fallback: previous geometry (8 chunks x 64 steps), fits 4 MB + 2 KB
        const size_t matBytes8 = (size_t)NB * 8 * 4096 * sizeof(f16_t);
        f16_t* wsCt = (f16_t*)d_ws;
        float* wsD  = (float*)((char*)d_ws + matBytes8);
        crf_chunk<8, 64><<<dim3(8, NB), 256, 0, stream>>>(feats, mask, trans, wsCt, wsD);
        crf_combine<8><<<NB, 64, 0, stream>>>(feats, mask, tags, trans, wsCt, wsD, out);
    }
}

// Round 4
// 121.550 us; speedup vs baseline: 1.1455x; 1.0815x over previous
//
#include <hip/hip_runtime.h>
#include <hip/hip_bf16.h>

#define T 50
#define NB 64
#define NS 512
#define START_TAG 48
#define STOP_TAG 49
#define NCH 8          // chunks
#define CHL 64         // steps per chunk
#define PITCH 72       // halfword pitch: 144 B rows -> every row 16B-aligned, even bank spread

typedef _Float16 f16_t;
typedef _Float16 f16x2 __attribute__((ext_vector_type(2)));
typedef _Float16 f16x4 __attribute__((ext_vector_type(4)));
typedef _Float16 f16x8 __attribute__((ext_vector_type(8)));
typedef float    f32x4 __attribute__((ext_vector_type(4)));

static constexpr float LOG2E = 1.4426950408889634f;
static constexpr float LN2F  = 0.6931471805599453f;
static constexpr float S_E   = 6.0f;     // static log2 shift folded out of E
#define NEG_BIG (-1.0e38f)

__device__ __forceinline__ float fexp2(float x) { return __builtin_amdgcn_exp2f(x); }
__device__ __forceinline__ float flog2(float x) { return __builtin_amdgcn_logf(x); }
__device__ __forceinline__ f16x2 bcast_h2(f16x2 v, int src) {
    unsigned u = __builtin_amdgcn_readlane(__builtin_bit_cast(unsigned, v), src);
    return __builtin_bit_cast(f16x2, u);
}
__device__ __forceinline__ f16x2 pack_h2(float a, float b) {
    return __builtin_bit_cast(f16x2, __builtin_amdgcn_cvt_pkrtz(a, b));
}

// Full-wave (64-lane) fmax via DPP (VALU pipe, ~40 cy chain) -> uniform value.
// row_shr:1/2/4/8 make lane15 of each 16-row hold the row max; row_bcast15
// merges row pairs; row_bcast31 merges halves; lane 63 holds the total.
// bound_ctrl=false + old=src => invalid lanes keep own value (identity for max).
__device__ __forceinline__ float wave_fmax_dpp(float x) {
#define DPP_STEP(ctrl)                                                        \
    do {                                                                      \
        int _s = __builtin_bit_cast(int, x);                                  \
        int _p = __builtin_amdgcn_update_dpp(_s, _s, (ctrl), 0xf, 0xf, false);\
        x = fmaxf(x, __builtin_bit_cast(float, _p));                          \
    } while (0)
    DPP_STEP(0x111);  // row_shr:1
    DPP_STEP(0x112);  // row_shr:2
    DPP_STEP(0x114);  // row_shr:4
    DPP_STEP(0x118);  // row_shr:8
    DPP_STEP(0x142);  // row_bcast:15
    DPP_STEP(0x143);  // row_bcast:31
#undef DPP_STEP
    return __builtin_bit_cast(float,
        __builtin_amdgcn_readlane(__builtin_bit_cast(int, x), 63));
}

// =====================================================================
// Kernel 1 (barrier-free steps): per (batch, chunk) compute
// P_c = prod_t (E * D_t) as CHL sequential 64x64x64 f16 MFMA products.
// KEY: in C' = C*(E*D), output rows == A-operand rows, so wave w's
// A-fragments come ONLY from its own previous output rows [16w,16w+16).
// Each wave keeps its 16x64 stripe in a private LDS region; same-wave
// lgkmcnt ordering replaces __syncthreads (2 barriers total: after
// preload, before epilogue). Renorm is per-wave (own max via DPP, own
// D accumulator); combine applies the per-16-row-block D.
//  - column permutation pi: MFMA slot n=16*c2+l15 holds actual column
//    4*l15+c2 -> lane's 4 outputs contiguous -> 1 ds_write_b64 per row,
//    column scales via 1 ds_read_b128.
//  - PITCH=72: 144 B rows -> A-read is one ds_read_b128 per kb (16B
//    aligned for every row), even bank distribution on read and write.
// =====================================================================
__global__ __launch_bounds__(256, 1)
void crf_chunk(const float* __restrict__ feats, const int* __restrict__ mask,
               const float* __restrict__ trans, f16_t* __restrict__ wsCt,
               float* __restrict__ wsD) {
    const int c    = blockIdx.x;          // chunk
    const int b    = blockIdx.y;          // batch
    const int tid  = threadIdx.x;
    const int w    = tid >> 6;
    const int lane = tid & 63;
    const int l15  = lane & 15;
    const int q    = lane >> 4;

    __shared__ f16_t sC[64 * PITCH];      // 4 private 16-row stripes (single-buffered)
    __shared__ float sF[CHL][64];         // 2^(f_t*log2e) per step/col (preloaded)
    __shared__ int   sMk[CHL];            // masks (preloaded)

    const int t0  = c * CHL + 1;
    const int nst = NS - t0 < CHL ? NS - t0 : CHL;

    // ---- E fragments, column-permuted. Slot n = 16*c2 + l15 -> actual
    // column j = 4*l15 + c2. Row index k = 32*kb + q*8 + jj (natural).
    f16x8 Efrag[2][4];
    #pragma unroll
    for (int kb = 0; kb < 2; kb++)
        #pragma unroll
        for (int c2 = 0; c2 < 4; c2++) {
            f16x8 v;
            const int j = 4 * l15 + c2;
            #pragma unroll
            for (int jj = 0; jj < 8; jj++) {
                int kk = 32 * kb + q * 8 + jj;
                float x = 0.f;
                if (kk < T && j < T) x = fexp2(fmaf(trans[kk * T + j], LOG2E, -S_E));
                v[jj] = (f16_t)x;
            }
            Efrag[kb][c2] = v;
        }

    // ---- bulk preload: feats block (exp2 once) + masks
    for (int r = w; r < CHL; r += 4) {
        int tl = t0 + r; tl = tl < NS ? tl : NS - 1;
        float fv = (lane < T && r < nst) ? feats[((size_t)b * NS + tl) * T + lane] : 0.f;
        sF[r][lane] = (lane < T && r < nst) ? fexp2(fv * LOG2E) : 0.f;
    }
    if (tid < CHL) {
        int tl = t0 + tid; tl = tl < NS ? tl : NS - 1;
        sMk[tid] = (tid < nst) ? mask[b * NS + tl] : 0;
    }

    // ---- init: C = I (wave w zeroes its own stripe; diag by row owner)
    for (int idx = tid; idx < 64 * PITCH; idx += 256) sC[idx] = (f16_t)0.f;
    if (tid < 64) sC[tid * PITCH + tid] = (f16_t)1.f;
    __syncthreads();                      // barrier #1 (sF/sMk/C visible)

    float D   = 0.f;
    float mxw = 1.f;                      // wave-uniform running stripe max
    int   mk  = sMk[0];

    for (int s = 0; s < nst; s++) {
        const bool doit = (mk != 0);
        mk = (s + 1 < CHL) ? sMk[s + 1] : 0;

        if (doit) {
            // descale from previous step's per-wave max (clamped pow2)
            int ebits = (int)((__float_as_uint(mxw) >> 23) & 255) - 127;
            ebits = ebits > 14 ? 14 : (ebits < -14 ? -14 : ebits);
            const float descale = __uint_as_float((unsigned)(127 - ebits) << 23);
            D += (float)ebits + S_E;

            // A fragments: own stripe, row 16w+l15, one b128 per kb
            const int abase = (16 * w + l15) * PITCH + 8 * q;
            f16x8 A0 = *(const f16x8*)&sC[abase];
            f16x8 A1 = *(const f16x8*)&sC[abase + 32];

            // 8 MFMAs: rows [16w,16w+16) x 4 col-blocks (slot space)
            f32x4 acc[4];
            #pragma unroll
            for (int c2 = 0; c2 < 4; c2++) {
                acc[c2] = __builtin_amdgcn_mfma_f32_16x16x32_f16(A0, Efrag[0][c2],
                                                                 (f32x4){0.f,0.f,0.f,0.f}, 0, 0, 0);
                acc[c2] = __builtin_amdgcn_mfma_f32_16x16x32_f16(A1, Efrag[1][c2],
                                                                 acc[c2], 0, 0, 0);
            }

            // column scales (actual cols 4*l15..+3) * descale, one b128 read
            f32x4 csv = *(const f32x4*)&sF[s][4 * l15];
            f32x4 cs2;
            #pragma unroll
            for (int c2 = 0; c2 < 4; c2++) cs2[c2] = csv[c2] * descale;

            // scale, track lane max, pack 4 contiguous cols -> b64 store/row
            float wmax = 0.f;
            #pragma unroll
            for (int r = 0; r < 4; r++) {
                f16x4 hv;
                #pragma unroll
                for (int c2 = 0; c2 < 4; c2++) {
                    float v = acc[c2][r] * cs2[c2];
                    wmax = fmaxf(wmax, v);
                    hv[c2] = (f16_t)v;     // RNE, matches previous numerics
                }
                *(f16x4*)&sC[(16 * w + 4 * q + r) * PITCH + 4 * l15] = hv;
            }

            // per-wave max via DPP (VALU pipe) - consumed next step
            mxw = wave_fmax_dpp(wmax);
        }
    }

    __syncthreads();                      // barrier #2 (epilogue reads all stripes)

    // ---- store C TRANSPOSED: wsCt[.. + col*64 + row] = C[row][col]
    {
        const int col = tid >> 2;
        const int r0  = (tid & 3) << 4;
        unsigned short tmp[16];
        #pragma unroll
        for (int r = 0; r < 16; r++)
            tmp[r] = __builtin_bit_cast(unsigned short, sC[(r0 + r) * PITCH + col]);
        f16_t* dst = wsCt + ((size_t)(b * NCH + c)) * 4096 + col * 64 + r0;
        ((int4*)dst)[0] = *(const int4*)&tmp[0];
        ((int4*)dst)[1] = *(const int4*)&tmp[8];
    }
    if (lane == 0) wsD[(b * NCH + c) * 4 + w] = D;   // per-wave shift
}

// =====================================================================
// Kernel 2: one wave per batch, no LDS, no barriers. Lane j holds column j
// of each chunk matrix (= C^T row j, contiguous 128 B) in registers,
// register-prefetched one chunk ahead. part = part (x) P_c via true-max
// shift + packed-f16 dot2 (25 x readlane + v_dot2_f32_f16).
// Changes: per-16-row-block shift Dq[k>>4] added to part BEFORE the
// max-shift (absorbs kernel 1's per-wave renorm); max via DPP not shfl.
// =====================================================================
__global__ __launch_bounds__(64, 1)
void crf_combine(const float* __restrict__ feats, const int* __restrict__ mask,
                 const int* __restrict__ tags, const float* __restrict__ trans,
                 const f16_t* __restrict__ wsCt, const float* __restrict__ wsD,
                 float* __restrict__ out) {
    const int b    = blockIdx.x;
    const int lane = threadIdx.x;

    // ---------------- gold score ----------------
    float gsum = 0.f;
    int   lcnt = 0;
    for (int s = lane; s < NS; s += 64) {
        int   m  = mask[b * NS + s];
        int   tg = tags[b * NS + s];
        int   pv = (s == 0) ? START_TAG : tags[b * NS + s - 1];
        float e  = feats[((size_t)b * NS + s) * T + tg];
        float tr = trans[pv * T + tg];
        if (m) { gsum += e + tr; lcnt += 1; }
    }
    #pragma unroll
    for (int off = 32; off > 0; off >>= 1) {
        gsum += __shfl_down(gsum, off, 64);
        lcnt += __shfl_down(lcnt, off, 64);
    }
    float goldb = 0.f;
    if (lane == 0) goldb = gsum + trans[tags[b * NS + lcnt - 1] * T + STOP_TAG];

    // ---------------- part init (t = 0), log2 domain ----------------
    float part = (lane < T)
        ? (feats[(size_t)b * NS * T + lane] + trans[START_TAG * T + lane]) * LOG2E
        : NEG_BIG;

    // ---------------- per-chunk per-row-block shifts ----------------
    float Dq[NCH];
    #pragma unroll
    for (int c = 0; c < NCH; c++)
        Dq[c] = wsD[(b * NCH + c) * 4 + (lane >> 4)];   // lane holds part_k, k=lane

    int cur[32], nxt[32];
    {
        const f16_t* src = wsCt + (size_t)b * NCH * 4096 + lane * 64;
        #pragma unroll
        for (int kk = 0; kk < 8; kk++)
            *(int4*)&cur[4 * kk] = ((const int4*)src)[kk];
    }

    #pragma unroll
    for (int c = 0; c < NCH; c++) {
        if (c + 1 < NCH) {
            const f16_t* src = wsCt + (size_t)(b * NCH + c + 1) * 4096 + lane * 64;
            #pragma unroll
            for (int kk = 0; kk < 8; kk++)
                *(int4*)&nxt[4 * kk] = ((const int4*)src)[kk];
        }

        // absorb per-row-block renorm, then true-max shift (DPP, uniform)
        float tmp = part + Dq[c];
        float sft = wave_fmax_dpp(tmp);
        float ex  = fexp2(tmp - sft);
        float exo = __shfl_xor(ex, 1, 64);
        f16x2 pk  = pack_h2(ex, exo);     // even lane 2k holds (ex[2k], ex[2k+1])

        float a0 = 0.f, a1 = 0.f, a2 = 0.f, a3 = 0.f;
        #pragma unroll
        for (int k = 0; k < 25; k += 4) {
            a0 = __builtin_amdgcn_fdot2(bcast_h2(pk, 2 * k), __builtin_bit_cast(f16x2, cur[k]), a0, false);
            if (k + 1 < 25) a1 = __builtin_amdgcn_fdot2(bcast_h2(pk, 2 * (k + 1)), __builtin_bit_cast(f16x2, cur[k + 1]), a1, false);
            if (k + 2 < 25) a2 = __builtin_amdgcn_fdot2(bcast_h2(pk, 2 * (k + 2)), __builtin_bit_cast(f16x2, cur[k + 2]), a2, false);
            if (k + 3 < 25) a3 = __builtin_amdgcn_fdot2(bcast_h2(pk, 2 * (k + 3)), __builtin_bit_cast(f16x2, cur[k + 3]), a3, false);
        }
        part = sft + flog2((a0 + a1) + (a2 + a3));

        if (c + 1 < NCH) {
            #pragma unroll
            for (int kk = 0; kk < 32; kk++) cur[kk] = nxt[kk];
        }
    }

    // ---------------- terminal LSE to STOP + output ----------------
    float v = (lane < T) ? part + trans[lane * T + STOP_TAG] * LOG2E : NEG_BIG;
    float mx = wave_fmax_dpp(v);
    float ee = (lane < T) ? fexp2(v - mx) : 0.f;
    #pragma unroll
    for (int off = 32; off > 0; off >>= 1) ee += __shfl_xor(ee, off, 64);
    if (lane == 0) {
        float fwd = (mx + flog2(ee)) * LN2F;   // back to nats
        atomicAdd(out, fwd - goldb);
    }
}

extern "C" void kernel_launch(void* const* d_in, const int* in_sizes, int n_in,
                              void* d_out, int out_size, void* d_ws, size_t ws_size,
                              hipStream_t stream) {
    const float* feats = (const float*)d_in[0];
    const int*   mask  = (const int*)d_in[1];
    const int*   tags  = (const int*)d_in[2];
    const float* trans = (const float*)d_in[3];
    float* out = (float*)d_out;

    // workspace: 64*8 chunk matrices (4 KB f16 each) + per-(b,c,wave) shifts
    f16_t* wsCt = (f16_t*)d_ws;
    float* wsD  = (float*)((char*)d_ws + (size_t)NB * NCH * 4096 * sizeof(f16_t));

    (void)hipMemsetAsync(out, 0, sizeof(float) * out_size, stream);
    crf_chunk<<<dim3(NCH, NB), 256, 0, stream>>>(feats, mask, trans, wsCt, wsD);
    crf_combine<<<NB, 64, 0, stream>>>(feats, mask, tags, trans, wsCt, wsD, out);
}

// Round 6
// 117.823 us; speedup vs baseline: 1.1817x; 1.0316x over previous
//
#include <hip/hip_runtime.h>
#include <hip/hip_bf16.h>

#define T 50
#define NB 64
#define NS 512
#define START_TAG 48
#define STOP_TAG 49
#define PITCH 72       // halfword pitch: 144 B rows -> every row 16B-aligned

typedef _Float16 f16_t;
typedef _Float16 f16x2 __attribute__((ext_vector_type(2)));
typedef _Float16 f16x4 __attribute__((ext_vector_type(4)));
typedef _Float16 f16x8 __attribute__((ext_vector_type(8)));
typedef float    f32x4 __attribute__((ext_vector_type(4)));

static constexpr float LOG2E = 1.4426950408889634f;
static constexpr float LN2F  = 0.6931471805599453f;
static constexpr float S_E   = 6.0f;     // static log2 shift folded out of E
#define NEG_BIG (-1.0e38f)

__device__ __forceinline__ float fexp2(float x) { return __builtin_amdgcn_exp2f(x); }
__device__ __forceinline__ float flog2(float x) { return __builtin_amdgcn_logf(x); }
__device__ __forceinline__ f16x2 bcast_h2(f16x2 v, int src) {
    unsigned u = __builtin_amdgcn_readlane(__builtin_bit_cast(unsigned, v), src);
    return __builtin_bit_cast(f16x2, u);
}
__device__ __forceinline__ f16x2 pack_h2(float a, float b) {
    return __builtin_bit_cast(f16x2, __builtin_amdgcn_cvt_pkrtz(a, b));
}

// Full-wave (64-lane) fmax via DPP (VALU pipe) -> uniform value via lane 63.
__device__ __forceinline__ float wave_fmax_dpp(float x) {
#define DPP_STEP(ctrl)                                                        \
    do {                                                                      \
        int _s = __builtin_bit_cast(int, x);                                  \
        int _p = __builtin_amdgcn_update_dpp(_s, _s, (ctrl), 0xf, 0xf, false);\
        x = fmaxf(x, __builtin_bit_cast(float, _p));                          \
    } while (0)
    DPP_STEP(0x111);  // row_shr:1
    DPP_STEP(0x112);  // row_shr:2
    DPP_STEP(0x114);  // row_shr:4
    DPP_STEP(0x118);  // row_shr:8
    DPP_STEP(0x142);  // row_bcast:15
    DPP_STEP(0x143);  // row_bcast:31
#undef DPP_STEP
    return __builtin_bit_cast(float,
        __builtin_amdgcn_readlane(__builtin_bit_cast(int, x), 63));
}

// =====================================================================
// Kernel 1 (barrier-free steps, slim VALU): per (batch, chunk) compute
// P_c = prod_t (E * D_t) as CHLT sequential 64x64x64 f16 MFMA products.
// Wave w's A-operand rows [16w,16w+16) are its OWN previous output ->
// private LDS stripe, no per-step __syncthreads (same-wave in-order LDS
// pipe gives RAW correctness). Renorm per-wave; combine absorbs the
// per-16-row-block shift.
//  - mask bitmap via ONE __ballot at preload: per-step doit is SALU,
//    no per-step LDS mask read.
//  - descale/ebits/D on SALU (mxw comes from readlane -> SGPR).
//  - column permutation pi: slot n=16*c2+l15 holds actual column
//    4*l15+c2 -> 1 ds_write_b64 per row; column scales via 1 b128 read.
//  - NCHT=16/CHLT=32 -> 1024 blocks = 4 blocks/CU, 4 free-running
//    chains per SIMD.
// =====================================================================
template<int NCHT, int CHLT>
__global__ __launch_bounds__(256, 1)
void crf_chunk(const float* __restrict__ feats, const int* __restrict__ mask,
               const float* __restrict__ trans, f16_t* __restrict__ wsCt,
               float* __restrict__ wsD) {
    const int c    = blockIdx.x;          // chunk
    const int b    = blockIdx.y;          // batch
    const int tid  = threadIdx.x;
    const int w    = tid >> 6;
    const int lane = tid & 63;
    const int l15  = lane & 15;
    const int q    = lane >> 4;

    __shared__ f16_t sC[64 * PITCH];      // 4 private 16-row stripes
    __shared__ float sF[CHLT][64];        // 2^(f_t*log2e) per step/col

    const int t0  = c * CHLT + 1;
    const int nst = NS - t0 < CHLT ? NS - t0 : CHLT;

    // ---- E fragments, column-permuted (slot n=16*c2+l15 -> col 4*l15+c2)
    f16x8 Efrag[2][4];
    #pragma unroll
    for (int kb = 0; kb < 2; kb++)
        #pragma unroll
        for (int c2 = 0; c2 < 4; c2++) {
            f16x8 v;
            const int j = 4 * l15 + c2;
            #pragma unroll
            for (int jj = 0; jj < 8; jj++) {
                int kk = 32 * kb + q * 8 + jj;
                float x = 0.f;
                if (kk < T && j < T) x = fexp2(fmaf(trans[kk * T + j], LOG2E, -S_E));
                v[jj] = (f16_t)x;
            }
            Efrag[kb][c2] = v;
        }

    // ---- bulk preload: feats block (exp2 once)
    for (int r = w; r < CHLT; r += 4) {
        int tl = t0 + r; tl = tl < NS ? tl : NS - 1;
        float fv = (lane < T && r < nst) ? feats[((size_t)b * NS + tl) * T + lane] : 0.f;
        sF[r][lane] = (lane < T && r < nst) ? fexp2(fv * LOG2E) : 0.f;
    }

    // ---- mask bitmap: bit s = mask[t0+s] (one ballot, then SALU per step)
    unsigned long long bm;
    {
        int tl = t0 + lane; tl = tl < NS ? tl : NS - 1;
        int mv = (lane < nst) ? mask[b * NS + tl] : 0;
        bm = __ballot(mv != 0);
    }

    // ---- init: C = I
    for (int idx = tid; idx < 64 * PITCH; idx += 256) sC[idx] = (f16_t)0.f;
    if (tid < 64) sC[tid * PITCH + tid] = (f16_t)1.f;
    __syncthreads();                      // barrier #1 (sF/C visible)

    float D   = 0.f;
    float mxw = 1.f;                      // wave-uniform running stripe max
    const int abase  = (16 * w + l15) * PITCH + 8 * q;
    const int sbase0 = (16 * w + 4 * q) * PITCH + 4 * l15;

    for (int s = 0; s < nst; s++) {
        if ((bm >> s) & 1ull) {
            // descale from previous step's per-wave max (SALU path)
            int ebits = (int)((__float_as_uint(mxw) >> 23) & 255) - 127;
            ebits = ebits > 14 ? 14 : (ebits < -14 ? -14 : ebits);
            const float descale = __uint_as_float((unsigned)(127 - ebits) << 23);
            D += (float)ebits + S_E;

            // column scales + A fragments (LDS reads batch together)
            f32x4 csv = *(const f32x4*)&sF[s][4 * l15];
            f16x8 A0  = *(const f16x8*)&sC[abase];
            f16x8 A1  = *(const f16x8*)&sC[abase + 32];

            // 8 MFMAs: rows [16w,16w+16) x 4 col-blocks (slot space)
            f32x4 acc[4];
            #pragma unroll
            for (int c2 = 0; c2 < 4; c2++) {
                acc[c2] = __builtin_amdgcn_mfma_f32_16x16x32_f16(A0, Efrag[0][c2],
                                                                 (f32x4){0.f,0.f,0.f,0.f}, 0, 0, 0);
                acc[c2] = __builtin_amdgcn_mfma_f32_16x16x32_f16(A1, Efrag[1][c2],
                                                                 acc[c2], 0, 0, 0);
            }

            f32x4 cs2;
            #pragma unroll
            for (int c2 = 0; c2 < 4; c2++) cs2[c2] = csv[c2] * descale;

            // scale, track lane max, pack 4 contiguous cols -> b64 store/row
            float wmax = 0.f;
            #pragma unroll
            for (int r = 0; r < 4; r++) {
                f16x4 hv;
                #pragma unroll
                for (int c2 = 0; c2 < 4; c2++) {
                    float v = acc[c2][r] * cs2[c2];
                    wmax = fmaxf(wmax, v);
                    hv[c2] = (f16_t)v;     // RNE
                }
                *(f16x4*)&sC[sbase0 + r * PITCH] = hv;
            }

            mxw = wave_fmax_dpp(wmax);     // off critical path (feeds s+1 post-MFMA)
        }
    }

    __syncthreads();                      // barrier #2 (epilogue reads all stripes)

    // ---- store C TRANSPOSED: wsCt[.. + col*64 + row] = C[row][col]
    {
        const int col = tid >> 2;
        const int r0  = (tid & 3) << 4;
        unsigned short tmp[16];
        #pragma unroll
        for (int r = 0; r < 16; r++)
            tmp[r] = __builtin_bit_cast(unsigned short, sC[(r0 + r) * PITCH + col]);
        f16_t* dst = wsCt + ((size_t)(b * NCHT + c)) * 4096 + col * 64 + r0;
        ((int4*)dst)[0] = *(const int4*)&tmp[0];
        ((int4*)dst)[1] = *(const int4*)&tmp[8];
    }
    if (lane == 0) wsD[(b * NCHT + c) * 4 + w] = D;   // per-wave shift
}

// =====================================================================
// Kernel 2: 2 waves per batch. Wave 0: part-chain over NCHT chunk
// matrices (lane j holds column j in registers, prefetched one chunk
// ahead; true-max shift via DPP; packed-f16 dot2). Wave 1: gold score
// concurrently. LDS handoff + one barrier at the end.
// =====================================================================
template<int NCHT>
__global__ __launch_bounds__(128, 1)
void crf_combine(const float* __restrict__ feats, const int* __restrict__ mask,
                 const int* __restrict__ tags, const float* __restrict__ trans,
                 const f16_t* __restrict__ wsCt, const float* __restrict__ wsD,
                 float* __restrict__ out) {
    const int b    = blockIdx.x;
    const int tid  = threadIdx.x;
    const int wv   = tid >> 6;
    const int lane = tid & 63;

    __shared__ float sGold;
    float fwd = 0.f;

    if (wv == 1) {
        // ---------------- gold score (wave 1) ----------------
        float gsum = 0.f;
        int   lcnt = 0;
        for (int s = lane; s < NS; s += 64) {
            int   m  = mask[b * NS + s];
            int   tg = tags[b * NS + s];
            int   pv = (s == 0) ? START_TAG : tags[b * NS + s - 1];
            float e  = feats[((size_t)b * NS + s) * T + tg];
            float tr = trans[pv * T + tg];
            if (m) { gsum += e + tr; lcnt += 1; }
        }
        #pragma unroll
        for (int off = 32; off > 0; off >>= 1) {
            gsum += __shfl_down(gsum, off, 64);
            lcnt += __shfl_down(lcnt, off, 64);
        }
        if (lane == 0) sGold = gsum + trans[tags[b * NS + lcnt - 1] * T + STOP_TAG];
    } else {
        // ---------------- part chain (wave 0), log2 domain ----------------
        float part = (lane < T)
            ? (feats[(size_t)b * NS * T + lane] + trans[START_TAG * T + lane]) * LOG2E
            : NEG_BIG;

        float Dq[NCHT];
        #pragma unroll
        for (int c = 0; c < NCHT; c++)
            Dq[c] = wsD[(b * NCHT + c) * 4 + (lane >> 4)];  // per-16-row-block shift

        int cur[32], nxt[32];
        {
            const f16_t* src = wsCt + (size_t)b * NCHT * 4096 + lane * 64;
            #pragma unroll
            for (int kk = 0; kk < 8; kk++)
                *(int4*)&cur[4 * kk] = ((const int4*)src)[kk];
        }

        #pragma unroll
        for (int c = 0; c < NCHT; c++) {
            if (c + 1 < NCHT) {
                const f16_t* src = wsCt + (size_t)(b * NCHT + c + 1) * 4096 + lane * 64;
                #pragma unroll
                for (int kk = 0; kk < 8; kk++)
                    *(int4*)&nxt[4 * kk] = ((const int4*)src)[kk];
            }

            // absorb per-row-block renorm, then true-max shift (DPP)
            float tmp = part + Dq[c];
            float sft = wave_fmax_dpp(tmp);
            float ex  = fexp2(tmp - sft);
            float exo = __shfl_xor(ex, 1, 64);
            f16x2 pk  = pack_h2(ex, exo);   // even lane 2k holds (ex[2k], ex[2k+1])

            float a0 = 0.f, a1 = 0.f, a2 = 0.f, a3 = 0.f;
            #pragma unroll
            for (int k = 0; k < 25; k += 4) {
                a0 = __builtin_amdgcn_fdot2(bcast_h2(pk, 2 * k), __builtin_bit_cast(f16x2, cur[k]), a0, false);
                if (k + 1 < 25) a1 = __builtin_amdgcn_fdot2(bcast_h2(pk, 2 * (k + 1)), __builtin_bit_cast(f16x2, cur[k + 1]), a1, false);
                if (k + 2 < 25) a2 = __builtin_amdgcn_fdot2(bcast_h2(pk, 2 * (k + 2)), __builtin_bit_cast(f16x2, cur[k + 2]), a2, false);
                if (k + 3 < 25) a3 = __builtin_amdgcn_fdot2(bcast_h2(pk, 2 * (k + 3)), __builtin_bit_cast(f16x2, cur[k + 3]), a3, false);
            }
            part = sft + flog2((a0 + a1) + (a2 + a3));

            if (c + 1 < NCHT) {
                #pragma unroll
                for (int kk = 0; kk < 32; kk++) cur[kk] = nxt[kk];
            }
        }

        // terminal LSE to STOP
        float v = (lane < T) ? part + trans[lane * T + STOP_TAG] * LOG2E : NEG_BIG;
        float mx = wave_fmax_dpp(v);
        float ee = (lane < T) ? fexp2(v - mx) : 0.f;
        #pragma unroll
        for (int off = 32; off > 0; off >>= 1) ee += __shfl_xor(ee, off, 64);
        fwd = (mx + flog2(ee)) * LN2F;      // nats (valid at lane 0)
    }

    __syncthreads();
    if (tid == 0) atomicAdd(out, fwd - sGold);
}

extern "C" void kernel_launch(void* const* d_in, const int* in_sizes, int n_in,
                              void* d_out, int out_size, void* d_ws, size_t ws_size,
                              hipStream_t stream) {
    const float* feats = (const float*)d_in[0];
    const int*   mask  = (const int*)d_in[1];
    const int*   tags  = (const int*)d_in[2];
    const float* trans = (const float*)d_in[3];
    float* out = (float*)d_out;

    (void)hipMemsetAsync(out, 0, sizeof(float) * out_size, stream);

    const size_t matBytes16 = (size_t)NB * 16 * 4096 * sizeof(f16_t);
    const size_t need16     = matBytes16 + (size_t)NB * 16 * 4 * sizeof(float);

    if (ws_size >= need16) {
        // preferred: 16 chunks x 32 steps -> 1024 blocks (4/CU), barrier-free
        f16_t* wsCt = (f16_t*)d_ws;
        float* wsD  = (float*)((char*)d_ws + matBytes16);
        crf_chunk<16, 32><<<dim3(16, NB), 256, 0, stream>>>(feats, mask, trans, wsCt, wsD);
        crf_combine<16><<<NB, 128, 0, stream>>>(feats, mask, tags, trans, wsCt, wsD, out);
    } else {
        // fallback: 8 chunks x 64 steps (fits 4 MB + 8 KB)
        const size_t matBytes8 = (size_t)NB * 8 * 4096 * sizeof(f16_t);
        f16_t* wsCt = (f16_t*)d_ws;
        float* wsD  = (float*)((char*)d_ws + matBytes8);
        crf_chunk<8, 64><<<dim3(8, NB), 256, 0, stream>>>(feats, mask, trans, wsCt, wsD);
        crf_combine<8><<<NB, 128, 0, stream>>>(feats, mask, tags, trans, wsCt, wsD, out);
    }
}